// Round 8
// baseline (196.513 us; speedup 1.0000x reference)
//
#include <hip/hip_runtime.h>
#include <hip/hip_bf16.h>
#include <math.h>

typedef __hip_bfloat16 bf16;
typedef __bf16  bf16x8 __attribute__((ext_vector_type(8)));
typedef float   f32x4  __attribute__((ext_vector_type(4)));

#define BB 2
#define NN 2048
#define DD 1024
#define HH 16
#define HD 64
#define LOG2E   1.44269504f
#define SCALE_Q 0.18033688f   /* 0.125 * log2(e), folded into q */

// async global->LDS, 16B/lane; LDS dest = wave-uniform base + lane*16
__device__ __forceinline__ void glds16(const bf16* g, bf16* l) {
    __builtin_amdgcn_global_load_lds((const __attribute__((address_space(1))) void*)g,
                                     (__attribute__((address_space(3))) void*)l, 16, 0, 0);
}
__device__ __forceinline__ unsigned short bfu(float x) {
    bf16 b = __float2bfloat16(x);
    return __builtin_bit_cast(unsigned short, b);
}

// ---------------------------------------------------------------------------
// prep (single launch): [0,2048) cast x ; [2048,3072) bias_perm PACKED BF16
// pairs (8-wave consumption order; halves the dominant attn traffic stream) ;
// [3072,3840) transpose Wqkv ; [3840,4096) coordproj.
// ---------------------------------------------------------------------------
__global__ __launch_bounds__(256) void prep(const float* __restrict__ x,
                                            const float* __restrict__ bias,
                                            const float* __restrict__ W,
                                            const float* __restrict__ coords,
                                            const float* __restrict__ relw,
                                            bf16* __restrict__ xb,
                                            unsigned* __restrict__ pbh,
                                            bf16* __restrict__ Wt,
                                            bf16* __restrict__ cpn) {
    __shared__ bf16 tsm[64][65];
    const int bid = blockIdx.x, tid = threadIdx.x;
    if (bid < 2048) {
        size_t i = ((size_t)bid * 256 + tid) * 8;
        float4 a = *(const float4*)(x + i);
        float4 b = *(const float4*)(x + i + 4);
        bf16 t[8];
        t[0] = __float2bfloat16(a.x); t[1] = __float2bfloat16(a.y);
        t[2] = __float2bfloat16(a.z); t[3] = __float2bfloat16(a.w);
        t[4] = __float2bfloat16(b.x); t[5] = __float2bfloat16(b.y);
        t[6] = __float2bfloat16(b.z); t[7] = __float2bfloat16(b.w);
        *(int4*)(xb + i) = *(int4*)t;
    } else if (bid < 3072) {
        // pbh[tt*8 + m] packs bf16(log2e*bias) rows (quad*4+(m&1)*2, +1) at
        // col kt*64+(m>>1)*16+l15 ; tt = ((Qb*32+kt)*8+wave)*64+lane
        int tt   = (bid - 2048) * 256 + tid;     // 0..262143
        int lane = tt & 63;
        int wave = (tt >> 6) & 7;
        int kt   = (tt >> 9) & 31;
        int Qb   = tt >> 14;
        int quad = lane >> 4, l15 = lane & 15;
        unsigned pk[8];
#pragma unroll
        for (int m = 0; m < 8; ++m) {
            int g = m >> 1, rp = m & 1;
            int q = Qb * 128 + wave * 16 + quad * 4 + rp * 2;
            int k = kt * 64 + g * 16 + l15;
            float v0 = LOG2E * bias[(size_t)q * NN + k];
            float v1 = LOG2E * bias[(size_t)(q + 1) * NN + k];
            pk[m] = (unsigned)bfu(v0) | ((unsigned)bfu(v1) << 16);
        }
        int4* dst = (int4*)(pbh + (size_t)tt * 8);
        dst[0] = ((int4*)pk)[0];
        dst[1] = ((int4*)pk)[1];
    } else if (bid < 3840) {
        int idx = bid - 3072;                    // 0..767
        int n0 = (idx % 48) * 64;
        int k0 = (idx / 48) * 64;
        int tx = tid & 63, tg = tid >> 6;
#pragma unroll
        for (int i = 0; i < 16; ++i) {
            int r = tg + i * 4;
            tsm[r][tx] = __float2bfloat16(W[(size_t)(k0 + r) * 3072 + n0 + tx]);
        }
        __syncthreads();
#pragma unroll
        for (int i = 0; i < 16; ++i) {
            int r = tg + i * 4;
            Wt[(size_t)(n0 + r) * 1024 + k0 + tx] = tsm[tx][r];
        }
    } else {
        int idx = (bid - 3840) * 256 + tid;      // 0..65535
        int n  = idx & (NN - 1);
        int bh = idx >> 11;
        int h  = bh & (HH - 1);
        int b  = bh >> 4;
        float acc = 0.f;
#pragma unroll
        for (int c = 0; c < 3; ++c)
            acc += coords[(size_t)(b * NN + n) * 3 + c] * relw[h * 3 + c];
        cpn[idx] = __float2bfloat16(-LOG2E * acc);
    }
}

// ---------------------------------------------------------------------------
// qkv GEMM v3: 128x128 tile, BK=32, TWO-PHASE double-buffered staging:
// one barrier per K-step; prefetch of tile k+1 issued right after the
// barrier so HBM/L2 latency hides under tile k's ds_read+MFMA (same dbuf
// pattern as the attn kernel). LDS 2x16KB=32KB. XCD m-grouped swizzle (R7).
// V written DIRECTLY TRANSPOSED (bh,d,n); q pre-scaled by SCALE_Q.
// ---------------------------------------------------------------------------
__global__ __launch_bounds__(256) void qkv_gemm(const bf16* __restrict__ X,
                                                const bf16* __restrict__ W,
                                                const float* __restrict__ bq,
                                                bf16* __restrict__ qo,
                                                bf16* __restrict__ ko,
                                                bf16* __restrict__ vt) {
    __shared__ __align__(16) bf16 As[2][128 * 32];
    __shared__ __align__(16) bf16 Bs[2][128 * 32];
    const int tid  = threadIdx.x;
    const int gid  = blockIdx.x + blockIdx.y * 24;   // 0..767
    const int xcd  = gid & 7;                        // HW round-robin XCD
    const int idx  = gid >> 3;                       // 0..95 within XCD
    const int n0   = (idx >> 2) * 128;               // n-block 0..23 (m-fastest order)
    const int m0   = (xcd * 4 + (idx & 3)) * 128;    // 4 contiguous m-panels per XCD
    const int wave = tid >> 6, lane = tid & 63, l15 = lane & 15, quad = lane >> 4;
    const int wm   = wave >> 1, wn = wave & 1;

    // hoisted staging geometry: 2 glds-pairs per wave, loop-invariant
    const int s0   = (wave * 2 + 0) * 64 + lane;     // 0..511
    const int r0   = s0 >> 2;
    const int c0   = (s0 & 3) ^ ((r0 >> 1) & 3);
    const int s1   = (wave * 2 + 1) * 64 + lane;
    const int r1   = s1 >> 2;
    const int c1   = (s1 & 3) ^ ((r1 >> 1) & 3);

#define QKV_STAGE(BUF, KT)                                                        \
    {                                                                             \
        glds16(X + (size_t)(m0 + r0) * 1024 + (KT) + c0 * 8,                      \
               As[BUF] + (wave * 2 + 0) * 512);                                   \
        glds16(W + (size_t)(n0 + r0) * 1024 + (KT) + c0 * 8,                      \
               Bs[BUF] + (wave * 2 + 0) * 512);                                   \
        glds16(X + (size_t)(m0 + r1) * 1024 + (KT) + c1 * 8,                      \
               As[BUF] + (wave * 2 + 1) * 512);                                   \
        glds16(W + (size_t)(n0 + r1) * 1024 + (KT) + c1 * 8,                      \
               Bs[BUF] + (wave * 2 + 1) * 512);                                   \
    }

    f32x4 acc[4][4];
    const f32x4 z4 = {0.f, 0.f, 0.f, 0.f};
#pragma unroll
    for (int i = 0; i < 4; ++i)
#pragma unroll
        for (int j = 0; j < 4; ++j) acc[i][j] = z4;

    // prologue: stage tile 0 into buffer 0
    QKV_STAGE(0, 0)

#define QKV_STEP(BUF, KTN)                                                        \
    {                                                                             \
        __syncthreads();   /* drains vmcnt: buf[BUF] ready; other buf free */     \
        if ((KTN) < 1024) QKV_STAGE((BUF) ^ 1, (KTN))                             \
        bf16x8 a[4], b[4];                                                        \
        _Pragma("unroll")                                                         \
        for (int mt = 0; mt < 4; ++mt) {                                          \
            int ra = wm * 64 + mt * 16 + l15;                                     \
            a[mt] = *(const bf16x8*)&As[BUF][ra * 32 + ((quad ^ ((ra >> 1) & 3)) * 8)]; \
        }                                                                         \
        _Pragma("unroll")                                                         \
        for (int nt = 0; nt < 4; ++nt) {                                          \
            int rb = wn * 64 + nt * 16 + l15;                                     \
            b[nt] = *(const bf16x8*)&Bs[BUF][rb * 32 + ((quad ^ ((rb >> 1) & 3)) * 8)]; \
        }                                                                         \
        _Pragma("unroll")                                                         \
        for (int mt = 0; mt < 4; ++mt)                                            \
            _Pragma("unroll")                                                     \
            for (int nt = 0; nt < 4; ++nt)                                        \
                acc[mt][nt] = __builtin_amdgcn_mfma_f32_16x16x32_bf16(a[mt], b[nt], acc[mt][nt], 0, 0, 0); \
    }

    for (int kt = 0; kt < 1024; kt += 64) {
        QKV_STEP(0, kt + 32)
        QKV_STEP(1, kt + 64)
    }
#undef QKV_STEP
#undef QKV_STAGE

#pragma unroll
    for (int nt = 0; nt < 4; ++nt) {
        int c    = n0 + wn * 64 + nt * 16 + l15;   // 0..3071, tsel uniform per nt
        int tsel = c >> 10;
        int rem  = c & 1023;
        int h    = rem >> 6, d = rem & 63;
        float bias = bq[c];
        float qs   = (tsel == 0) ? SCALE_Q : 1.0f;
#pragma unroll
        for (int mt = 0; mt < 4; ++mt)
#pragma unroll
            for (int r = 0; r < 4; ++r) {
                int m = m0 + wm * 64 + mt * 16 + quad * 4 + r;   // 0..4095
                int b = m >> 11, n = m & (NN - 1);
                bf16 val = __float2bfloat16((acc[mt][nt][r] + bias) * qs);
                if (tsel == 2)
                    vt[((size_t)(b * HH + h) * HD + d) * NN + n] = val;
                else
                    ((tsel == 1) ? ko : qo)[((size_t)(b * HH + h) * NN + n) * HD + d] = val;
            }
    }
}

// ---------------------------------------------------------------------------
// flash attention v5: R1 structure (512 thr = 8 waves x 16 q, 128 q/block,
// grid 512) + PACKED BF16 bias (2 int4 loads/tile instead of 4; unpack via
// shift/mask into the MFMA C-operand). Bias stream 536->268 MB logical.
// LDS 55296 B.
// ---------------------------------------------------------------------------
__global__ __launch_bounds__(512, 4) void attn(const bf16* __restrict__ Q,
                                               const bf16* __restrict__ K,
                                               const bf16* __restrict__ Vt_g,
                                               const bf16* __restrict__ cpn_g,
                                               const unsigned* __restrict__ pbh,
                                               float* __restrict__ out) {
    __shared__ __align__(16) bf16 Ks[2][64 * 64];
    __shared__ __align__(16) bf16 Vs[2][64 * 64];      // [d][key]
    __shared__ __align__(16) unsigned PsW[8][16 * 36]; // packed P, per-wave
    __shared__ __align__(16) bf16 cpl[NN];             // -log2e * cp[bh][*]
    const int tid  = threadIdx.x;
    const int Qb   = blockIdx.x;           // 0..15
    const int bh   = blockIdx.y;           // 0..31
    const int b    = bh >> 4, h = bh & 15;
    const int q0   = Qb * 128;
    const int wave = tid >> 6, lane = tid & 63, l15 = lane & 15, quad = lane >> 4;
    const size_t base = (size_t)bh * NN * HD;

    // stage cp row (4 KB) with waves 0..3 (wave-uniform branch)
    if (wave < 4)
        glds16(cpn_g + bh * NN + (wave * 64 + lane) * 8, cpl + wave * 512);

    // Q fragments: 16 q-rows per wave, in registers for the whole kernel
    const int qrow = q0 + wave * 16 + l15;
    bf16x8 qf0 = *(const bf16x8*)&Q[base + (size_t)qrow * HD + quad * 8];
    bf16x8 qf1 = *(const bf16x8*)&Q[base + (size_t)qrow * HD + 32 + quad * 8];

    // hoisted staging geometry (one glds per buffer per wave)
    const int ps   = wave * 64 + lane;     // 0..511
    const int prow = ps >> 3;              // 0..63
    const int pcol = (ps & 7) ^ (prow & 7);

    // prologue: stage tile 0 into buffer 0
    glds16(K    + base + (size_t)prow * HD + pcol * 8, Ks[0] + wave * 512);
    glds16(Vt_g + base + (size_t)prow * NN + pcol * 8, Vs[0] + wave * 512);

    // bias: permuted packed bf16, register double-buffer. tile stride 4096 u32.
    const unsigned* bptr = pbh + ((((size_t)Qb * 32) * 8 + wave) * 64 + lane) * 8;
    unsigned bvA[8], bvB[8];
    *(int4*)&bvA[0] = ((const int4*)bptr)[0];
    *(int4*)&bvA[4] = ((const int4*)bptr)[1];

    const f32x4 z4 = {0.f, 0.f, 0.f, 0.f};
    f32x4 l4 = z4;
    f32x4 o[4];
#pragma unroll
    for (int t = 0; t < 4; ++t) o[t] = z4;

#define ATTN_TILE(T, CUR, BVC, BVN)                                               \
    {                                                                             \
        __syncthreads();   /* buf[CUR] ready (vmcnt drained); buf[CUR^1] free */  \
        if ((T) < 31) {    /* prefetch K/V tile T+1 and bias T+1 */               \
            int kk1 = ((T) + 1) * 64;                                             \
            glds16(K    + base + (size_t)(kk1 + prow) * HD + pcol * 8,            \
                   Ks[(CUR) ^ 1] + wave * 512);                                   \
            glds16(Vt_g + base + (size_t)prow * NN + kk1 + pcol * 8,              \
                   Vs[(CUR) ^ 1] + wave * 512);                                   \
            const unsigned* bp = bptr + (size_t)((T) + 1) * 4096;                 \
            *(int4*)&BVN[0] = ((const int4*)bp)[0];                               \
            *(int4*)&BVN[4] = ((const int4*)bp)[1];                               \
        }                                                                         \
        /* --- QK^T with C = bias' + mg (bias unpacked bf16->f32 into C) */       \
        f32x4 p4[4];                                                              \
        _Pragma("unroll")                                                         \
        for (int g = 0; g < 4; ++g) {                                             \
            float mgv = __bfloat162float(cpl[(T) * 64 + g * 16 + l15]);           \
            unsigned ba = BVC[g * 2], bb2 = BVC[g * 2 + 1];                       \
            f32x4 c0;                                                             \
            c0[0] = __builtin_bit_cast(float, ba << 16) + mgv;                    \
            c0[1] = __builtin_bit_cast(float, ba & 0xffff0000u) + mgv;            \
            c0[2] = __builtin_bit_cast(float, bb2 << 16) + mgv;                   \
            c0[3] = __builtin_bit_cast(float, bb2 & 0xffff0000u) + mgv;           \
            int krow = g * 16 + l15, sw = krow & 7;                               \
            bf16x8 k0 = *(const bf16x8*)&Ks[(CUR)][krow * 64 + ((quad ^ sw) * 8)];         \
            bf16x8 k1 = *(const bf16x8*)&Ks[(CUR)][krow * 64 + (((4 + quad) ^ sw) * 8)];   \
            f32x4 s4 = __builtin_amdgcn_mfma_f32_16x16x32_bf16(qf0, k0, c0, 0, 0, 0);      \
            s4 = __builtin_amdgcn_mfma_f32_16x16x32_bf16(qf1, k1, s4, 0, 0, 0);   \
            f32x4 e;                                                              \
            e[0] = __builtin_amdgcn_exp2f(s4[0]);                                 \
            e[1] = __builtin_amdgcn_exp2f(s4[1]);                                 \
            e[2] = __builtin_amdgcn_exp2f(s4[2]);                                 \
            e[3] = __builtin_amdgcn_exp2f(s4[3]);                                 \
            p4[g] = e;                                                            \
            l4 = l4 + e;                                                          \
        }                                                                         \
        /* --- packed P write (8 b32), one wait, read back as A-frags */          \
        _Pragma("unroll")                                                         \
        for (int g2 = 0; g2 < 2; ++g2)                                            \
            _Pragma("unroll")                                                     \
            for (int r = 0; r < 4; ++r) {                                         \
                unsigned pk = (unsigned)bfu(p4[g2][r]) |                          \
                              ((unsigned)bfu(p4[g2 + 2][r]) << 16);               \
                PsW[wave][(quad * 4 + r) * 36 + g2 * 16 + l15] = pk;              \
            }                                                                     \
        asm volatile("s_waitcnt lgkmcnt(0)" ::: "memory");                        \
        const int4* pr = (const int4*)&PsW[wave][l15 * 36 + quad * 8];            \
        int4 da = pr[0], db = pr[1];                                              \
        union { unsigned u[4]; bf16x8 v; } u0, u1;                                \
        u0.u[0] = __builtin_amdgcn_perm(da.y, da.x, 0x05040100u);                 \
        u0.u[1] = __builtin_amdgcn_perm(da.w, da.z, 0x05040100u);                 \
        u0.u[2] = __builtin_amdgcn_perm(db.y, db.x, 0x05040100u);                 \
        u0.u[3] = __builtin_amdgcn_perm(db.w, db.z, 0x05040100u);                 \
        u1.u[0] = __builtin_amdgcn_perm(da.y, da.x, 0x07060302u);                 \
        u1.u[1] = __builtin_amdgcn_perm(da.w, da.z, 0x07060302u);                 \
        u1.u[2] = __builtin_amdgcn_perm(db.y, db.x, 0x07060302u);                 \
        u1.u[3] = __builtin_amdgcn_perm(db.w, db.z, 0x07060302u);                 \
        /* --- PV (V frags loaded at use) */                                      \
        __builtin_amdgcn_s_setprio(1);                                            \
        _Pragma("unroll")                                                         \
        for (int tt = 0; tt < 4; ++tt) {                                          \
            int drow = tt * 16 + l15, sw2 = drow & 7;                             \
            bf16x8 v0 = *(const bf16x8*)&Vs[(CUR)][drow * 64 + ((quad ^ sw2) * 8)];        \
            bf16x8 v1 = *(const bf16x8*)&Vs[(CUR)][drow * 64 + (((4 + quad) ^ sw2) * 8)];  \
            o[tt] = __builtin_amdgcn_mfma_f32_16x16x32_bf16(u0.v, v0, o[tt], 0, 0, 0);     \
            o[tt] = __builtin_amdgcn_mfma_f32_16x16x32_bf16(u1.v, v1, o[tt], 0, 0, 0);     \
        }                                                                         \
        __builtin_amdgcn_s_setprio(0);                                            \
    }

    for (int t = 0; t < 32; t += 2) {
        ATTN_TILE(t,     0, bvA, bvB)
        ATTN_TILE(t + 1, 1, bvB, bvA)
    }
#undef ATTN_TILE

    // final l reduction (16 lanes per quad-row) + fp32 stores
    float l_loc[4] = {l4[0], l4[1], l4[2], l4[3]};
#pragma unroll
    for (int r = 0; r < 4; ++r) {
#pragma unroll
        for (int d = 1; d < 16; d <<= 1)
            l_loc[r] += __shfl_xor(l_loc[r], d, 64);
        float inv = 1.0f / l_loc[r];
        int qq = q0 + wave * 16 + quad * 4 + r;
#pragma unroll
        for (int tt = 0; tt < 4; ++tt)
            out[((size_t)(b * NN + qq)) * DD + h * HD + tt * 16 + l15] =
                o[tt][r] * inv;
    }
}

// ---------------------------------------------------------------------------
extern "C" void kernel_launch(void* const* d_in, const int* in_sizes, int n_in,
                              void* d_out, int out_size, void* d_ws, size_t ws_size,
                              hipStream_t stream) {
    const float* x      = (const float*)d_in[0];
    const float* coords = (const float*)d_in[1];
    const float* abias  = (const float*)d_in[2];
    const float* Wqkv   = (const float*)d_in[3];
    const float* bqkv   = (const float*)d_in[4];
    const float* relw   = (const float*)d_in[5];
    float* out = (float*)d_out;

    char* ws = (char*)d_ws;
    bf16*     xb  = (bf16*)(ws);                      // 8 MB
    bf16*     qw  = (bf16*)(ws + 8388608);            // 8 MB
    bf16*     kw  = (bf16*)(ws + 16777216);           // 8 MB
    bf16*     vt  = (bf16*)(ws + 25165824);           // 8 MB (bh,d,n) via gemm epilogue
    bf16*     Wt  = (bf16*)(ws + 33554432);           // 6 MB
    unsigned* pbh = (unsigned*)(ws + 39845888);       // 8.4 MB permuted bias packed bf16
    bf16*     cpb = (bf16*)(ws + 56623104);           // 128 KB

    prep    <<<dim3(4096),   256, 0, stream>>>(x, abias, Wqkv, coords, relw,
                                               xb, pbh, Wt, cpb);
    qkv_gemm<<<dim3(24, 32), 256, 0, stream>>>(xb, Wt, bqkv, qw, kw, vt);
    attn    <<<dim3(16, 32), 512, 0, stream>>>(qw, kw, vt, cpb, pbh, out);
}

// Round 10
// 193.574 us; speedup vs baseline: 1.0152x; 1.0152x over previous
//
#include <hip/hip_runtime.h>
#include <hip/hip_bf16.h>
#include <math.h>

typedef __hip_bfloat16 bf16;
typedef __bf16  bf16x8 __attribute__((ext_vector_type(8)));
typedef float   f32x4  __attribute__((ext_vector_type(4)));

#define BB 2
#define NN 2048
#define DD 1024
#define HH 16
#define HD 64
#define LOG2E   1.44269504f
#define SCALE_Q 0.18033688f   /* 0.125 * log2(e), folded into q */

// async global->LDS, 16B/lane; LDS dest = wave-uniform base + lane*16
__device__ __forceinline__ void glds16(const bf16* g, bf16* l) {
    __builtin_amdgcn_global_load_lds((const __attribute__((address_space(1))) void*)g,
                                     (__attribute__((address_space(3))) void*)l, 16, 0, 0);
}
__device__ __forceinline__ unsigned short bfu(float x) {
    bf16 b = __float2bfloat16(x);
    return __builtin_bit_cast(unsigned short, b);
}

// ---------------------------------------------------------------------------
// prep (single launch): [0,2048) cast x ; [2048,3072) bias_perm PACKED BF16,
// laid out for the PERMUTED-KEY swapped-QK attn: lane(quad,l15) of wave at
// tile kt holds keys kt*64 + {quad*8+0..7, 32+quad*8+0..7} for q=Qb*128+
// wave*16+l15 ; [3072,3840) transpose Wqkv ; [3840,4096) coordproj.
// ---------------------------------------------------------------------------
__global__ __launch_bounds__(256) void prep(const float* __restrict__ x,
                                            const float* __restrict__ bias,
                                            const float* __restrict__ W,
                                            const float* __restrict__ coords,
                                            const float* __restrict__ relw,
                                            bf16* __restrict__ xb,
                                            unsigned* __restrict__ pbh,
                                            bf16* __restrict__ Wt,
                                            bf16* __restrict__ cpn) {
    __shared__ bf16 tsm[64][65];
    const int bid = blockIdx.x, tid = threadIdx.x;
    if (bid < 2048) {
        size_t i = ((size_t)bid * 256 + tid) * 8;
        float4 a = *(const float4*)(x + i);
        float4 b = *(const float4*)(x + i + 4);
        bf16 t[8];
        t[0] = __float2bfloat16(a.x); t[1] = __float2bfloat16(a.y);
        t[2] = __float2bfloat16(a.z); t[3] = __float2bfloat16(a.w);
        t[4] = __float2bfloat16(b.x); t[5] = __float2bfloat16(b.y);
        t[6] = __float2bfloat16(b.z); t[7] = __float2bfloat16(b.w);
        *(int4*)(xb + i) = *(int4*)t;
    } else if (bid < 3072) {
        // tt = ((Qb*32+kt)*8+wave)*64+lane ; q = Qb*128+wave*16+l15
        // pk[g*2+h] packs keys kb + (g>>1)*32 + (g&1)*4 + 2h, +1 ; kb=kt*64+quad*8
        int tt   = (bid - 2048) * 256 + tid;     // 0..262143
        int lane = tt & 63;
        int wave = (tt >> 6) & 7;
        int kt   = (tt >> 9) & 31;
        int Qb   = tt >> 14;
        int quad = lane >> 4, l15 = lane & 15;
        int q    = Qb * 128 + wave * 16 + l15;
        const float* brow = bias + (size_t)q * NN + kt * 64 + quad * 8;
        unsigned pk[8];
#pragma unroll
        for (int g = 0; g < 4; ++g) {
            int off = (g >> 1) * 32 + (g & 1) * 4;
            const float4 bv = *(const float4*)(brow + off);
            pk[g * 2]     = (unsigned)bfu(LOG2E * bv.x) | ((unsigned)bfu(LOG2E * bv.y) << 16);
            pk[g * 2 + 1] = (unsigned)bfu(LOG2E * bv.z) | ((unsigned)bfu(LOG2E * bv.w) << 16);
        }
        int4* dst = (int4*)(pbh + (size_t)tt * 8);
        dst[0] = ((int4*)pk)[0];
        dst[1] = ((int4*)pk)[1];
    } else if (bid < 3840) {
        int idx = bid - 3072;                    // 0..767
        int n0 = (idx % 48) * 64;
        int k0 = (idx / 48) * 64;
        int tx = tid & 63, tg = tid >> 6;
#pragma unroll
        for (int i = 0; i < 16; ++i) {
            int r = tg + i * 4;
            tsm[r][tx] = __float2bfloat16(W[(size_t)(k0 + r) * 3072 + n0 + tx]);
        }
        __syncthreads();
#pragma unroll
        for (int i = 0; i < 16; ++i) {
            int r = tg + i * 4;
            Wt[(size_t)(n0 + r) * 1024 + k0 + tx] = tsm[tx][r];
        }
    } else {
        int idx = (bid - 3840) * 256 + tid;      // 0..65535
        int n  = idx & (NN - 1);
        int bh = idx >> 11;
        int h  = bh & (HH - 1);
        int b  = bh >> 4;
        float acc = 0.f;
#pragma unroll
        for (int c = 0; c < 3; ++c)
            acc += coords[(size_t)(b * NN + n) * 3 + c] * relw[h * 3 + c];
        cpn[idx] = __float2bfloat16(-LOG2E * acc);
    }
}

// ---------------------------------------------------------------------------
// qkv GEMM (R7 version): 128x128 tile, BK=32, single-buffered, glds w=16,
// swizzle c^=((row>>1)&3), XCD m-grouped block swizzle. V written DIRECTLY
// TRANSPOSED (bh,d,n); q pre-scaled by SCALE_Q.
// ---------------------------------------------------------------------------
__global__ __launch_bounds__(256) void qkv_gemm(const bf16* __restrict__ X,
                                                const bf16* __restrict__ W,
                                                const float* __restrict__ bq,
                                                bf16* __restrict__ qo,
                                                bf16* __restrict__ ko,
                                                bf16* __restrict__ vt) {
    __shared__ __align__(16) bf16 As[128 * 32];
    __shared__ __align__(16) bf16 Bs[128 * 32];
    const int tid  = threadIdx.x;
    const int gid  = blockIdx.x + blockIdx.y * 24;   // 0..767
    const int xcd  = gid & 7;                        // HW round-robin XCD
    const int idx  = gid >> 3;                       // 0..95 within XCD
    const int n0   = (idx >> 2) * 128;               // n-block 0..23 (m-fastest order)
    const int m0   = (xcd * 4 + (idx & 3)) * 128;    // 4 contiguous m-panels per XCD
    const int wave = tid >> 6, lane = tid & 63, l15 = lane & 15, quad = lane >> 4;
    const int wm   = wave >> 1, wn = wave & 1;

    f32x4 acc[4][4];
    const f32x4 z4 = {0.f, 0.f, 0.f, 0.f};
#pragma unroll
    for (int i = 0; i < 4; ++i)
#pragma unroll
        for (int j = 0; j < 4; ++j) acc[i][j] = z4;

    for (int kt = 0; kt < 1024; kt += 32) {
        __syncthreads();
#pragma unroll
        for (int j = 0; j < 2; ++j) {
            int s   = (wave * 2 + j) * 64 + lane;       // 0..511
            int row = s >> 2;                           // 0..127
            int c   = (s & 3) ^ ((row >> 1) & 3);       // swizzled col-block
            glds16(X + (size_t)(m0 + row) * 1024 + kt + c * 8, As + (wave * 2 + j) * 512);
            glds16(W + (size_t)(n0 + row) * 1024 + kt + c * 8, Bs + (wave * 2 + j) * 512);
        }
        __syncthreads();

        bf16x8 a[4], b[4];
#pragma unroll
        for (int mt = 0; mt < 4; ++mt) {
            int ra = wm * 64 + mt * 16 + l15;
            a[mt] = *(const bf16x8*)&As[ra * 32 + ((quad ^ ((ra >> 1) & 3)) * 8)];
        }
#pragma unroll
        for (int nt = 0; nt < 4; ++nt) {
            int rb = wn * 64 + nt * 16 + l15;
            b[nt] = *(const bf16x8*)&Bs[rb * 32 + ((quad ^ ((rb >> 1) & 3)) * 8)];
        }
#pragma unroll
        for (int mt = 0; mt < 4; ++mt)
#pragma unroll
            for (int nt = 0; nt < 4; ++nt)
                acc[mt][nt] = __builtin_amdgcn_mfma_f32_16x16x32_bf16(a[mt], b[nt], acc[mt][nt], 0, 0, 0);
    }

#pragma unroll
    for (int nt = 0; nt < 4; ++nt) {
        int c    = n0 + wn * 64 + nt * 16 + l15;   // 0..3071, tsel uniform per nt
        int tsel = c >> 10;
        int rem  = c & 1023;
        int h    = rem >> 6, d = rem & 63;
        float bias = bq[c];
        float qs   = (tsel == 0) ? SCALE_Q : 1.0f;
#pragma unroll
        for (int mt = 0; mt < 4; ++mt)
#pragma unroll
            for (int r = 0; r < 4; ++r) {
                int m = m0 + wm * 64 + mt * 16 + quad * 4 + r;   // 0..4095
                int b = m >> 11, n = m & (NN - 1);
                bf16 val = __float2bfloat16((acc[mt][nt][r] + bias) * qs);
                if (tsel == 2)
                    vt[((size_t)(b * HH + h) * HD + d) * NN + n] = val;
                else
                    ((tsel == 1) ? ko : qo)[((size_t)(b * HH + h) * NN + n) * HD + d] = val;
            }
    }
}

// ---------------------------------------------------------------------------
// flash attention v7: swapped QK^T with PERMUTED KEY ROWS so the PV B-operand
// is lane-local — ZERO cross-lane ops for the P transpose. mfma g loads K
// rows krow = (g>>1)*32 + (l15>>2)*8 + (g&1)*4 + (l15&3); the resulting
// P^T rows land so that lane(quad,l15) holds exactly keys {quad*8+0..7} and
// {32+quad*8+0..7} -> B0=w32[0..3], B1=w32[4..7] directly. No PsW buffer,
// no lgkmcnt(0) drain. K-read swizzle fK=(l15>>2)|((l15&1)<<2) (2-way, free);
// K staged with fstage(row)=((row>>3)&3)|((row&1)<<2); V unchanged (row&7).
// LDS 36 KB. 512 thr = 8 waves x 16 q, 128 q/block, grid 512.
// ---------------------------------------------------------------------------
__global__ __launch_bounds__(512, 4) void attn(const bf16* __restrict__ Q,
                                               const bf16* __restrict__ K,
                                               const bf16* __restrict__ Vt_g,
                                               const bf16* __restrict__ cpn_g,
                                               const unsigned* __restrict__ pbh,
                                               float* __restrict__ out) {
    __shared__ __align__(16) bf16 Ks[2][64 * 64];
    __shared__ __align__(16) bf16 Vs[2][64 * 64];      // [d][key]
    __shared__ __align__(16) bf16 cpl[NN];             // -log2e * cp[bh][*]
    const int tid  = threadIdx.x;
    const int Qb   = blockIdx.x;           // 0..15
    const int bh   = blockIdx.y;           // 0..31
    const int b    = bh >> 4, h = bh & 15;
    const int q0   = Qb * 128;
    const int wave = tid >> 6, lane = tid & 63, l15 = lane & 15, quad = lane >> 4;
    const size_t base = (size_t)bh * NN * HD;

    // stage cp row (4 KB) with waves 0..3 (wave-uniform branch)
    if (wave < 4)
        glds16(cpn_g + bh * NN + (wave * 64 + lane) * 8, cpl + wave * 512);

    // Q fragments: 16 q-rows per wave, in registers for the whole kernel
    const int qrow = q0 + wave * 16 + l15;
    bf16x8 qf0 = *(const bf16x8*)&Q[base + (size_t)qrow * HD + quad * 8];
    bf16x8 qf1 = *(const bf16x8*)&Q[base + (size_t)qrow * HD + 32 + quad * 8];

    // staging geometry (one glds per buffer per wave); K and V use
    // DIFFERENT swizzles (K: fstage, V: row&7)
    const int ps    = wave * 64 + lane;     // 0..511
    const int prow  = ps >> 3;              // 0..63
    const int pcolV = (ps & 7) ^ (prow & 7);
    const int pcolK = (ps & 7) ^ (((prow >> 3) & 3) | ((prow & 1) << 2));

    // prologue: stage tile 0 into buffer 0
    glds16(K    + base + (size_t)prow * HD + pcolK * 8, Ks[0] + wave * 512);
    glds16(Vt_g + base + (size_t)prow * NN + pcolV * 8, Vs[0] + wave * 512);

    // bias: permuted packed bf16 (permuted-key layout), register dbuf.
    const unsigned* bptr = pbh + ((((size_t)Qb * 32) * 8 + wave) * 64 + lane) * 8;
    unsigned bvA[8], bvB[8];
    *(int4*)&bvA[0] = ((const int4*)bptr)[0];
    *(int4*)&bvA[4] = ((const int4*)bptr)[1];

    // loop-invariant K-read geometry
    const int lrow = ((l15 >> 2) << 3) + (l15 & 3);          // row offset per g
    const int fK   = (l15 >> 2) | ((l15 & 1) << 2);          // read swizzle
    const int ck0  = (quad ^ fK) * 8;                        // chunk 0..3
    const int ck1  = ((4 + quad) ^ fK) * 8;                  // chunk 4..7

    const f32x4 z4 = {0.f, 0.f, 0.f, 0.f};
    float l_acc = 0.f;
    f32x4 o[4];
#pragma unroll
    for (int t = 0; t < 4; ++t) o[t] = z4;

#define ATTN_TILE(T, CUR, BVC, BVN)                                               \
    {                                                                             \
        __syncthreads();   /* buf[CUR] ready (vmcnt drained); buf[CUR^1] free */  \
        if ((T) < 31) {    /* prefetch K/V tile T+1 and bias T+1 */               \
            int kk1 = ((T) + 1) * 64;                                             \
            glds16(K    + base + (size_t)(kk1 + prow) * HD + pcolK * 8,           \
                   Ks[(CUR) ^ 1] + wave * 512);                                   \
            glds16(Vt_g + base + (size_t)prow * NN + kk1 + pcolV * 8,             \
                   Vs[(CUR) ^ 1] + wave * 512);                                   \
            const unsigned* bp = bptr + (size_t)((T) + 1) * 4096;                 \
            *(int4*)&BVN[0] = ((const int4*)bp)[0];                               \
            *(int4*)&BVN[4] = ((const int4*)bp)[1];                               \
        }                                                                         \
        /* --- swapped QK^T, permuted key rows. D row quad*4+r <-> key        */  \
        /*     kb_g + quad*8 + (g&1)*4 + r, kb_g = (g>>1)*32                  */  \
        unsigned w32[8];                                                          \
        _Pragma("unroll")                                                         \
        for (int g = 0; g < 4; ++g) {                                             \
            const int kb = (g >> 1) * 32 + (g & 1) * 4;                           \
            ushort4 mgu = *(const ushort4*)&cpl[(T) * 64 + kb + quad * 8];        \
            unsigned ba = BVC[g * 2], bb2 = BVC[g * 2 + 1];                       \
            f32x4 c0;                                                             \
            c0[0] = __builtin_bit_cast(float, ba << 16)                           \
                  + __builtin_bit_cast(float, (unsigned)mgu.x << 16);             \
            c0[1] = __builtin_bit_cast(float, ba & 0xffff0000u)                   \
                  + __builtin_bit_cast(float, (unsigned)mgu.y << 16);             \
            c0[2] = __builtin_bit_cast(float, bb2 << 16)                          \
                  + __builtin_bit_cast(float, (unsigned)mgu.z << 16);             \
            c0[3] = __builtin_bit_cast(float, bb2 & 0xffff0000u)                  \
                  + __builtin_bit_cast(float, (unsigned)mgu.w << 16);             \
            int krow = kb + lrow;                                                 \
            bf16x8 k0 = *(const bf16x8*)&Ks[(CUR)][krow * 64 + ck0];              \
            bf16x8 k1 = *(const bf16x8*)&Ks[(CUR)][krow * 64 + ck1];              \
            f32x4 s4 = __builtin_amdgcn_mfma_f32_16x16x32_bf16(k0, qf0, c0, 0, 0, 0);      \
            s4 = __builtin_amdgcn_mfma_f32_16x16x32_bf16(k1, qf1, s4, 0, 0, 0);   \
            f32x4 e;                                                              \
            e[0] = __builtin_amdgcn_exp2f(s4[0]);                                 \
            e[1] = __builtin_amdgcn_exp2f(s4[1]);                                 \
            e[2] = __builtin_amdgcn_exp2f(s4[2]);                                 \
            e[3] = __builtin_amdgcn_exp2f(s4[3]);                                 \
            l_acc += (e[0] + e[1]) + (e[2] + e[3]);                               \
            w32[g * 2]     = (unsigned)bfu(e[0]) | ((unsigned)bfu(e[1]) << 16);   \
            w32[g * 2 + 1] = (unsigned)bfu(e[2]) | ((unsigned)bfu(e[3]) << 16);   \
        }                                                                         \
        /* --- PV B-operand is lane-local: B0=w32[0..3], B1=w32[4..7] */          \
        union { unsigned u[4]; bf16x8 v; } B0, B1;                                \
        B0.u[0] = w32[0]; B0.u[1] = w32[1]; B0.u[2] = w32[2]; B0.u[3] = w32[3];   \
        B1.u[0] = w32[4]; B1.u[1] = w32[5]; B1.u[2] = w32[6]; B1.u[3] = w32[7];   \
        /* --- PV: O^T[d][q] = V^T(A) x P^T(B) */                                 \
        __builtin_amdgcn_s_setprio(1);                                            \
        _Pragma("unroll")                                                         \
        for (int tt = 0; tt < 4; ++tt) {                                          \
            int drow = tt * 16 + l15, sw2 = drow & 7;                             \
            bf16x8 v0 = *(const bf16x8*)&Vs[(CUR)][drow * 64 + ((quad ^ sw2) * 8)];        \
            bf16x8 v1 = *(const bf16x8*)&Vs[(CUR)][drow * 64 + (((4 + quad) ^ sw2) * 8)];  \
            o[tt] = __builtin_amdgcn_mfma_f32_16x16x32_bf16(v0, B0.v, o[tt], 0, 0, 0);     \
            o[tt] = __builtin_amdgcn_mfma_f32_16x16x32_bf16(v1, B1.v, o[tt], 0, 0, 0);     \
        }                                                                         \
        __builtin_amdgcn_s_setprio(0);                                            \
    }

    for (int t = 0; t < 32; t += 2) {
        ATTN_TILE(t,     0, bvA, bvB)
        ATTN_TILE(t + 1, 1, bvB, bvA)
    }
#undef ATTN_TILE

    // l: reduce across the 4 quads holding the same q (=l15)
    l_acc += __shfl_xor(l_acc, 16, 64);
    l_acc += __shfl_xor(l_acc, 32, 64);
    const float inv = 1.0f / l_acc;

    // stores: o[tt][r] = O[d=tt*16+quad*4+r][q=l15] -> dwordx4 per tt
    const int qq = q0 + wave * 16 + l15;
#pragma unroll
    for (int tt = 0; tt < 4; ++tt) {
        f32x4 ov;
        ov[0] = o[tt][0] * inv; ov[1] = o[tt][1] * inv;
        ov[2] = o[tt][2] * inv; ov[3] = o[tt][3] * inv;
        *(f32x4*)&out[((size_t)(b * NN + qq)) * DD + h * HD + tt * 16 + quad * 4] = ov;
    }
}

// ---------------------------------------------------------------------------
extern "C" void kernel_launch(void* const* d_in, const int* in_sizes, int n_in,
                              void* d_out, int out_size, void* d_ws, size_t ws_size,
                              hipStream_t stream) {
    const float* x      = (const float*)d_in[0];
    const float* coords = (const float*)d_in[1];
    const float* abias  = (const float*)d_in[2];
    const float* Wqkv   = (const float*)d_in[3];
    const float* bqkv   = (const float*)d_in[4];
    const float* relw   = (const float*)d_in[5];
    float* out = (float*)d_out;

    char* ws = (char*)d_ws;
    bf16*     xb  = (bf16*)(ws);                      // 8 MB
    bf16*     qw  = (bf16*)(ws + 8388608);            // 8 MB
    bf16*     kw  = (bf16*)(ws + 16777216);           // 8 MB
    bf16*     vt  = (bf16*)(ws + 25165824);           // 8 MB (bh,d,n) via gemm epilogue
    bf16*     Wt  = (bf16*)(ws + 33554432);           // 6 MB
    unsigned* pbh = (unsigned*)(ws + 39845888);       // 8.4 MB permuted bias packed bf16
    bf16*     cpb = (bf16*)(ws + 56623104);           // 128 KB

    prep    <<<dim3(4096),   256, 0, stream>>>(x, abias, Wqkv, coords, relw,
                                               xb, pbh, Wt, cpb);
    qkv_gemm<<<dim3(24, 32), 256, 0, stream>>>(xb, Wt, bqkv, qw, kw, vt);
    attn    <<<dim3(16, 32), 512, 0, stream>>>(qw, kw, vt, cpb, pbh, out);
}

// Round 11
// 191.913 us; speedup vs baseline: 1.0240x; 1.0087x over previous
//
#include <hip/hip_runtime.h>
#include <hip/hip_bf16.h>
#include <math.h>

typedef __hip_bfloat16 bf16;
typedef __bf16  bf16x8 __attribute__((ext_vector_type(8)));
typedef float   f32x4  __attribute__((ext_vector_type(4)));

#define BB 2
#define NN 2048
#define DD 1024
#define HH 16
#define HD 64
#define LOG2E   1.44269504f
#define SCALE_Q 0.18033688f   /* 0.125 * log2(e), folded into q */

// async global->LDS, 16B/lane; LDS dest = wave-uniform base + lane*16
__device__ __forceinline__ void glds16(const bf16* g, bf16* l) {
    __builtin_amdgcn_global_load_lds((const __attribute__((address_space(1))) void*)g,
                                     (__attribute__((address_space(3))) void*)l, 16, 0, 0);
}
__device__ __forceinline__ unsigned short bfu(float x) {
    bf16 b = __float2bfloat16(x);
    return __builtin_bit_cast(unsigned short, b);
}

// ---------------------------------------------------------------------------
// prep (single launch): [0,2048) cast x ; [2048,3072) bias_perm PACKED BF16,
// laid out for the PERMUTED-KEY swapped-QK attn: lane(quad,l15) of wave at
// tile kt holds keys kt*64 + {quad*8+0..7, 32+quad*8+0..7} for q=Qb*128+
// wave*16+l15 ; [3072,3840) transpose Wqkv ; [3840,4096) coordproj.
// ---------------------------------------------------------------------------
__global__ __launch_bounds__(256) void prep(const float* __restrict__ x,
                                            const float* __restrict__ bias,
                                            const float* __restrict__ W,
                                            const float* __restrict__ coords,
                                            const float* __restrict__ relw,
                                            bf16* __restrict__ xb,
                                            unsigned* __restrict__ pbh,
                                            bf16* __restrict__ Wt,
                                            bf16* __restrict__ cpn) {
    __shared__ bf16 tsm[64][65];
    const int bid = blockIdx.x, tid = threadIdx.x;
    if (bid < 2048) {
        size_t i = ((size_t)bid * 256 + tid) * 8;
        float4 a = *(const float4*)(x + i);
        float4 b = *(const float4*)(x + i + 4);
        bf16 t[8];
        t[0] = __float2bfloat16(a.x); t[1] = __float2bfloat16(a.y);
        t[2] = __float2bfloat16(a.z); t[3] = __float2bfloat16(a.w);
        t[4] = __float2bfloat16(b.x); t[5] = __float2bfloat16(b.y);
        t[6] = __float2bfloat16(b.z); t[7] = __float2bfloat16(b.w);
        *(int4*)(xb + i) = *(int4*)t;
    } else if (bid < 3072) {
        // tt = ((Qb*32+kt)*8+wave)*64+lane ; q = Qb*128+wave*16+l15
        // pk[g*2+h] packs keys kb + 2h, +1 at base kt*64+quad*8, kb=(g>>1)*32+(g&1)*4
        int tt   = (bid - 2048) * 256 + tid;     // 0..262143
        int lane = tt & 63;
        int wave = (tt >> 6) & 7;
        int kt   = (tt >> 9) & 31;
        int Qb   = tt >> 14;
        int quad = lane >> 4, l15 = lane & 15;
        int q    = Qb * 128 + wave * 16 + l15;
        const float* brow = bias + (size_t)q * NN + kt * 64 + quad * 8;
        unsigned pk[8];
#pragma unroll
        for (int g = 0; g < 4; ++g) {
            int off = (g >> 1) * 32 + (g & 1) * 4;
            const float4 bv = *(const float4*)(brow + off);
            pk[g * 2]     = (unsigned)bfu(LOG2E * bv.x) | ((unsigned)bfu(LOG2E * bv.y) << 16);
            pk[g * 2 + 1] = (unsigned)bfu(LOG2E * bv.z) | ((unsigned)bfu(LOG2E * bv.w) << 16);
        }
        int4* dst = (int4*)(pbh + (size_t)tt * 8);
        dst[0] = ((int4*)pk)[0];
        dst[1] = ((int4*)pk)[1];
    } else if (bid < 3840) {
        int idx = bid - 3072;                    // 0..767
        int n0 = (idx % 48) * 64;
        int k0 = (idx / 48) * 64;
        int tx = tid & 63, tg = tid >> 6;
#pragma unroll
        for (int i = 0; i < 16; ++i) {
            int r = tg + i * 4;
            tsm[r][tx] = __float2bfloat16(W[(size_t)(k0 + r) * 3072 + n0 + tx]);
        }
        __syncthreads();
#pragma unroll
        for (int i = 0; i < 16; ++i) {
            int r = tg + i * 4;
            Wt[(size_t)(n0 + r) * 1024 + k0 + tx] = tsm[tx][r];
        }
    } else {
        int idx = (bid - 3840) * 256 + tid;      // 0..65535
        int n  = idx & (NN - 1);
        int bh = idx >> 11;
        int h  = bh & (HH - 1);
        int b  = bh >> 4;
        float acc = 0.f;
#pragma unroll
        for (int c = 0; c < 3; ++c)
            acc += coords[(size_t)(b * NN + n) * 3 + c] * relw[h * 3 + c];
        cpn[idx] = __float2bfloat16(-LOG2E * acc);
    }
}

// ---------------------------------------------------------------------------
// qkv GEMM (R7 version): 128x128 tile, BK=32, single-buffered, glds w=16,
// swizzle c^=((row>>1)&3), XCD m-grouped block swizzle. V written DIRECTLY
// TRANSPOSED (bh,d,n); q pre-scaled by SCALE_Q.
// ---------------------------------------------------------------------------
__global__ __launch_bounds__(256) void qkv_gemm(const bf16* __restrict__ X,
                                                const bf16* __restrict__ W,
                                                const float* __restrict__ bq,
                                                bf16* __restrict__ qo,
                                                bf16* __restrict__ ko,
                                                bf16* __restrict__ vt) {
    __shared__ __align__(16) bf16 As[128 * 32];
    __shared__ __align__(16) bf16 Bs[128 * 32];
    const int tid  = threadIdx.x;
    const int gid  = blockIdx.x + blockIdx.y * 24;   // 0..767
    const int xcd  = gid & 7;                        // HW round-robin XCD
    const int idx  = gid >> 3;                       // 0..95 within XCD
    const int n0   = (idx >> 2) * 128;               // n-block 0..23 (m-fastest order)
    const int m0   = (xcd * 4 + (idx & 3)) * 128;    // 4 contiguous m-panels per XCD
    const int wave = tid >> 6, lane = tid & 63, l15 = lane & 15, quad = lane >> 4;
    const int wm   = wave >> 1, wn = wave & 1;

    f32x4 acc[4][4];
    const f32x4 z4 = {0.f, 0.f, 0.f, 0.f};
#pragma unroll
    for (int i = 0; i < 4; ++i)
#pragma unroll
        for (int j = 0; j < 4; ++j) acc[i][j] = z4;

    for (int kt = 0; kt < 1024; kt += 32) {
        __syncthreads();
#pragma unroll
        for (int j = 0; j < 2; ++j) {
            int s   = (wave * 2 + j) * 64 + lane;       // 0..511
            int row = s >> 2;                           // 0..127
            int c   = (s & 3) ^ ((row >> 1) & 3);       // swizzled col-block
            glds16(X + (size_t)(m0 + row) * 1024 + kt + c * 8, As + (wave * 2 + j) * 512);
            glds16(W + (size_t)(n0 + row) * 1024 + kt + c * 8, Bs + (wave * 2 + j) * 512);
        }
        __syncthreads();

        bf16x8 a[4], b[4];
#pragma unroll
        for (int mt = 0; mt < 4; ++mt) {
            int ra = wm * 64 + mt * 16 + l15;
            a[mt] = *(const bf16x8*)&As[ra * 32 + ((quad ^ ((ra >> 1) & 3)) * 8)];
        }
#pragma unroll
        for (int nt = 0; nt < 4; ++nt) {
            int rb = wn * 64 + nt * 16 + l15;
            b[nt] = *(const bf16x8*)&Bs[rb * 32 + ((quad ^ ((rb >> 1) & 3)) * 8)];
        }
#pragma unroll
        for (int mt = 0; mt < 4; ++mt)
#pragma unroll
            for (int nt = 0; nt < 4; ++nt)
                acc[mt][nt] = __builtin_amdgcn_mfma_f32_16x16x32_bf16(a[mt], b[nt], acc[mt][nt], 0, 0, 0);
    }

#pragma unroll
    for (int nt = 0; nt < 4; ++nt) {
        int c    = n0 + wn * 64 + nt * 16 + l15;   // 0..3071, tsel uniform per nt
        int tsel = c >> 10;
        int rem  = c & 1023;
        int h    = rem >> 6, d = rem & 63;
        float bias = bq[c];
        float qs   = (tsel == 0) ? SCALE_Q : 1.0f;
#pragma unroll
        for (int mt = 0; mt < 4; ++mt)
#pragma unroll
            for (int r = 0; r < 4; ++r) {
                int m = m0 + wm * 64 + mt * 16 + quad * 4 + r;   // 0..4095
                int b = m >> 11, n = m & (NN - 1);
                bf16 val = __float2bfloat16((acc[mt][nt][r] + bias) * qs);
                if (tsel == 2)
                    vt[((size_t)(b * HH + h) * HD + d) * NN + n] = val;
                else
                    ((tsel == 1) ? ko : qo)[((size_t)(b * HH + h) * NN + n) * HD + d] = val;
            }
    }
}

// ---------------------------------------------------------------------------
// flash attention v8: v7 (swapped QK^T, permuted key rows, zero-shuffle P
// transpose) with the K swizzle FIXED for bank conflicts: consecutive lanes
// now hit 8 distinct 16B granule slots.
//   read  swizzle fK     = (l15&3) | (((l15>>2)&1)<<2)
//   stage swizzle fstage = (row&3) | (((row>>3)&1)<<2)
// (fstage(krow) == fK(l15) since krow = kb + 8*(l15>>2) + (l15&3), kb&3==0,
// (kb>>3)&1==0.) V swizzle unchanged (row&7, already conflict-free).
// LDS 36 KB. 512 thr = 8 waves x 16 q, 128 q/block, grid 512.
// ---------------------------------------------------------------------------
__global__ __launch_bounds__(512, 4) void attn(const bf16* __restrict__ Q,
                                               const bf16* __restrict__ K,
                                               const bf16* __restrict__ Vt_g,
                                               const bf16* __restrict__ cpn_g,
                                               const unsigned* __restrict__ pbh,
                                               float* __restrict__ out) {
    __shared__ __align__(16) bf16 Ks[2][64 * 64];
    __shared__ __align__(16) bf16 Vs[2][64 * 64];      // [d][key]
    __shared__ __align__(16) bf16 cpl[NN];             // -log2e * cp[bh][*]
    const int tid  = threadIdx.x;
    const int Qb   = blockIdx.x;           // 0..15
    const int bh   = blockIdx.y;           // 0..31
    const int b    = bh >> 4, h = bh & 15;
    const int q0   = Qb * 128;
    const int wave = tid >> 6, lane = tid & 63, l15 = lane & 15, quad = lane >> 4;
    const size_t base = (size_t)bh * NN * HD;

    // stage cp row (4 KB) with waves 0..3 (wave-uniform branch)
    if (wave < 4)
        glds16(cpn_g + bh * NN + (wave * 64 + lane) * 8, cpl + wave * 512);

    // Q fragments: 16 q-rows per wave, in registers for the whole kernel
    const int qrow = q0 + wave * 16 + l15;
    bf16x8 qf0 = *(const bf16x8*)&Q[base + (size_t)qrow * HD + quad * 8];
    bf16x8 qf1 = *(const bf16x8*)&Q[base + (size_t)qrow * HD + 32 + quad * 8];

    // staging geometry (one glds per buffer per wave); K and V use
    // DIFFERENT swizzles (K: fstage, V: row&7)
    const int ps    = wave * 64 + lane;     // 0..511
    const int prow  = ps >> 3;              // 0..63
    const int pcolV = (ps & 7) ^ (prow & 7);
    const int pcolK = (ps & 7) ^ ((prow & 3) | (((prow >> 3) & 1) << 2));

    // prologue: stage tile 0 into buffer 0
    glds16(K    + base + (size_t)prow * HD + pcolK * 8, Ks[0] + wave * 512);
    glds16(Vt_g + base + (size_t)prow * NN + pcolV * 8, Vs[0] + wave * 512);

    // bias: permuted packed bf16 (permuted-key layout), register dbuf.
    const unsigned* bptr = pbh + ((((size_t)Qb * 32) * 8 + wave) * 64 + lane) * 8;
    unsigned bvA[8], bvB[8];
    *(int4*)&bvA[0] = ((const int4*)bptr)[0];
    *(int4*)&bvA[4] = ((const int4*)bptr)[1];

    // loop-invariant K-read geometry
    const int lrow = ((l15 >> 2) << 3) + (l15 & 3);          // row offset per g
    const int fK   = (l15 & 3) | (((l15 >> 2) & 1) << 2);    // read swizzle (conflict-free)
    const int ck0  = (quad ^ fK) * 8;                        // chunk 0..3
    const int ck1  = ((4 + quad) ^ fK) * 8;                  // chunk 4..7

    const f32x4 z4 = {0.f, 0.f, 0.f, 0.f};
    float l_acc = 0.f;
    f32x4 o[4];
#pragma unroll
    for (int t = 0; t < 4; ++t) o[t] = z4;

#define ATTN_TILE(T, CUR, BVC, BVN)                                               \
    {                                                                             \
        __syncthreads();   /* buf[CUR] ready (vmcnt drained); buf[CUR^1] free */  \
        if ((T) < 31) {    /* prefetch K/V tile T+1 and bias T+1 */               \
            int kk1 = ((T) + 1) * 64;                                             \
            glds16(K    + base + (size_t)(kk1 + prow) * HD + pcolK * 8,           \
                   Ks[(CUR) ^ 1] + wave * 512);                                   \
            glds16(Vt_g + base + (size_t)prow * NN + kk1 + pcolV * 8,             \
                   Vs[(CUR) ^ 1] + wave * 512);                                   \
            const unsigned* bp = bptr + (size_t)((T) + 1) * 4096;                 \
            *(int4*)&BVN[0] = ((const int4*)bp)[0];                               \
            *(int4*)&BVN[4] = ((const int4*)bp)[1];                               \
        }                                                                         \
        /* --- swapped QK^T, permuted key rows. D row quad*4+r <-> key        */  \
        /*     kb_g + quad*8 + r, kb_g = (g>>1)*32 + (g&1)*4                  */  \
        unsigned w32[8];                                                          \
        _Pragma("unroll")                                                         \
        for (int g = 0; g < 4; ++g) {                                             \
            const int kb = (g >> 1) * 32 + (g & 1) * 4;                           \
            ushort4 mgu = *(const ushort4*)&cpl[(T) * 64 + kb + quad * 8];        \
            unsigned ba = BVC[g * 2], bb2 = BVC[g * 2 + 1];                       \
            f32x4 c0;                                                             \
            c0[0] = __builtin_bit_cast(float, ba << 16)                           \
                  + __builtin_bit_cast(float, (unsigned)mgu.x << 16);             \
            c0[1] = __builtin_bit_cast(float, ba & 0xffff0000u)                   \
                  + __builtin_bit_cast(float, (unsigned)mgu.y << 16);             \
            c0[2] = __builtin_bit_cast(float, bb2 << 16)                          \
                  + __builtin_bit_cast(float, (unsigned)mgu.z << 16);             \
            c0[3] = __builtin_bit_cast(float, bb2 & 0xffff0000u)                  \
                  + __builtin_bit_cast(float, (unsigned)mgu.w << 16);             \
            int krow = kb + lrow;                                                 \
            bf16x8 k0 = *(const bf16x8*)&Ks[(CUR)][krow * 64 + ck0];              \
            bf16x8 k1 = *(const bf16x8*)&Ks[(CUR)][krow * 64 + ck1];              \
            f32x4 s4 = __builtin_amdgcn_mfma_f32_16x16x32_bf16(k0, qf0, c0, 0, 0, 0);      \
            s4 = __builtin_amdgcn_mfma_f32_16x16x32_bf16(k1, qf1, s4, 0, 0, 0);   \
            f32x4 e;                                                              \
            e[0] = __builtin_amdgcn_exp2f(s4[0]);                                 \
            e[1] = __builtin_amdgcn_exp2f(s4[1]);                                 \
            e[2] = __builtin_amdgcn_exp2f(s4[2]);                                 \
            e[3] = __builtin_amdgcn_exp2f(s4[3]);                                 \
            l_acc += (e[0] + e[1]) + (e[2] + e[3]);                               \
            w32[g * 2]     = (unsigned)bfu(e[0]) | ((unsigned)bfu(e[1]) << 16);   \
            w32[g * 2 + 1] = (unsigned)bfu(e[2]) | ((unsigned)bfu(e[3]) << 16);   \
        }                                                                         \
        /* --- PV B-operand is lane-local: B0=w32[0..3], B1=w32[4..7] */          \
        union { unsigned u[4]; bf16x8 v; } B0, B1;                                \
        B0.u[0] = w32[0]; B0.u[1] = w32[1]; B0.u[2] = w32[2]; B0.u[3] = w32[3];   \
        B1.u[0] = w32[4]; B1.u[1] = w32[5]; B1.u[2] = w32[6]; B1.u[3] = w32[7];   \
        /* --- PV: O^T[d][q] = V^T(A) x P^T(B) */                                 \
        __builtin_amdgcn_s_setprio(1);                                            \
        _Pragma("unroll")                                                         \
        for (int tt = 0; tt < 4; ++tt) {                                          \
            int drow = tt * 16 + l15, sw2 = drow & 7;                             \
            bf16x8 v0 = *(const bf16x8*)&Vs[(CUR)][drow * 64 + ((quad ^ sw2) * 8)];        \
            bf16x8 v1 = *(const bf16x8*)&Vs[(CUR)][drow * 64 + (((4 + quad) ^ sw2) * 8)];  \
            o[tt] = __builtin_amdgcn_mfma_f32_16x16x32_bf16(v0, B0.v, o[tt], 0, 0, 0);     \
            o[tt] = __builtin_amdgcn_mfma_f32_16x16x32_bf16(v1, B1.v, o[tt], 0, 0, 0);     \
        }                                                                         \
        __builtin_amdgcn_s_setprio(0);                                            \
    }

    for (int t = 0; t < 32; t += 2) {
        ATTN_TILE(t,     0, bvA, bvB)
        ATTN_TILE(t + 1, 1, bvB, bvA)
    }
#undef ATTN_TILE

    // l: reduce across the 4 quads holding the same q (=l15)
    l_acc += __shfl_xor(l_acc, 16, 64);
    l_acc += __shfl_xor(l_acc, 32, 64);
    const float inv = 1.0f / l_acc;

    // stores: o[tt][r] = O[d=tt*16+quad*4+r][q=l15] -> dwordx4 per tt
    const int qq = q0 + wave * 16 + l15;
#pragma unroll
    for (int tt = 0; tt < 4; ++tt) {
        f32x4 ov;
        ov[0] = o[tt][0] * inv; ov[1] = o[tt][1] * inv;
        ov[2] = o[tt][2] * inv; ov[3] = o[tt][3] * inv;
        *(f32x4*)&out[((size_t)(b * NN + qq)) * DD + h * HD + tt * 16 + quad * 4] = ov;
    }
}

// ---------------------------------------------------------------------------
extern "C" void kernel_launch(void* const* d_in, const int* in_sizes, int n_in,
                              void* d_out, int out_size, void* d_ws, size_t ws_size,
                              hipStream_t stream) {
    const float* x      = (const float*)d_in[0];
    const float* coords = (const float*)d_in[1];
    const float* abias  = (const float*)d_in[2];
    const float* Wqkv   = (const float*)d_in[3];
    const float* bqkv   = (const float*)d_in[4];
    const float* relw   = (const float*)d_in[5];
    float* out = (float*)d_out;

    char* ws = (char*)d_ws;
    bf16*     xb  = (bf16*)(ws);                      // 8 MB
    bf16*     qw  = (bf16*)(ws + 8388608);            // 8 MB
    bf16*     kw  = (bf16*)(ws + 16777216);           // 8 MB
    bf16*     vt  = (bf16*)(ws + 25165824);           // 8 MB (bh,d,n) via gemm epilogue
    bf16*     Wt  = (bf16*)(ws + 33554432);           // 6 MB
    unsigned* pbh = (unsigned*)(ws + 39845888);       // 8.4 MB permuted bias packed bf16
    bf16*     cpb = (bf16*)(ws + 56623104);           // 128 KB

    prep    <<<dim3(4096),   256, 0, stream>>>(x, abias, Wqkv, coords, relw,
                                               xb, pbh, Wt, cpb);
    qkv_gemm<<<dim3(24, 32), 256, 0, stream>>>(xb, Wt, bqkv, qw, kw, vt);
    attn    <<<dim3(16, 32), 512, 0, stream>>>(qw, kw, vt, cpb, pbh, out);
}

// Round 12
// 189.505 us; speedup vs baseline: 1.0370x; 1.0127x over previous
//
#include <hip/hip_runtime.h>
#include <hip/hip_bf16.h>
#include <math.h>

typedef __hip_bfloat16 bf16;
typedef __bf16  bf16x8 __attribute__((ext_vector_type(8)));
typedef float   f32x4  __attribute__((ext_vector_type(4)));

#define BB 2
#define NN 2048
#define DD 1024
#define HH 16
#define HD 64
#define LOG2E   1.44269504f
#define SCALE_Q 0.18033688f   /* 0.125 * log2(e), folded into q */

// async global->LDS, 16B/lane; LDS dest = wave-uniform base + lane*16
__device__ __forceinline__ void glds16(const bf16* g, bf16* l) {
    __builtin_amdgcn_global_load_lds((const __attribute__((address_space(1))) void*)g,
                                     (__attribute__((address_space(3))) void*)l, 16, 0, 0);
}
__device__ __forceinline__ unsigned short bfu(float x) {
    bf16 b = __float2bfloat16(x);
    return __builtin_bit_cast(unsigned short, b);
}

// ---------------------------------------------------------------------------
// prep (single launch): [0,2048) cast x ; [2048,3072) bias_perm PACKED BF16,
// laid out for the PERMUTED-KEY swapped-QK attn: lane(quad,l15) of wave at
// tile kt holds keys kt*64 + {quad*8+0..7, 32+quad*8+0..7} for q=Qb*128+
// wave*16+l15 ; [3072,3840) transpose Wqkv ; [3840,4096) coordproj.
// ---------------------------------------------------------------------------
__global__ __launch_bounds__(256) void prep(const float* __restrict__ x,
                                            const float* __restrict__ bias,
                                            const float* __restrict__ W,
                                            const float* __restrict__ coords,
                                            const float* __restrict__ relw,
                                            bf16* __restrict__ xb,
                                            unsigned* __restrict__ pbh,
                                            bf16* __restrict__ Wt,
                                            bf16* __restrict__ cpn) {
    __shared__ bf16 tsm[64][65];
    const int bid = blockIdx.x, tid = threadIdx.x;
    if (bid < 2048) {
        size_t i = ((size_t)bid * 256 + tid) * 8;
        float4 a = *(const float4*)(x + i);
        float4 b = *(const float4*)(x + i + 4);
        bf16 t[8];
        t[0] = __float2bfloat16(a.x); t[1] = __float2bfloat16(a.y);
        t[2] = __float2bfloat16(a.z); t[3] = __float2bfloat16(a.w);
        t[4] = __float2bfloat16(b.x); t[5] = __float2bfloat16(b.y);
        t[6] = __float2bfloat16(b.z); t[7] = __float2bfloat16(b.w);
        *(int4*)(xb + i) = *(int4*)t;
    } else if (bid < 3072) {
        // tt = ((Qb*32+kt)*8+wave)*64+lane ; q = Qb*128+wave*16+l15
        // pk[g*2+h] packs keys kb + 2h, +1 at base kt*64+quad*8, kb=(g>>1)*32+(g&1)*4
        int tt   = (bid - 2048) * 256 + tid;     // 0..262143
        int lane = tt & 63;
        int wave = (tt >> 6) & 7;
        int kt   = (tt >> 9) & 31;
        int Qb   = tt >> 14;
        int quad = lane >> 4, l15 = lane & 15;
        int q    = Qb * 128 + wave * 16 + l15;
        const float* brow = bias + (size_t)q * NN + kt * 64 + quad * 8;
        unsigned pk[8];
#pragma unroll
        for (int g = 0; g < 4; ++g) {
            int off = (g >> 1) * 32 + (g & 1) * 4;
            const float4 bv = *(const float4*)(brow + off);
            pk[g * 2]     = (unsigned)bfu(LOG2E * bv.x) | ((unsigned)bfu(LOG2E * bv.y) << 16);
            pk[g * 2 + 1] = (unsigned)bfu(LOG2E * bv.z) | ((unsigned)bfu(LOG2E * bv.w) << 16);
        }
        int4* dst = (int4*)(pbh + (size_t)tt * 8);
        dst[0] = ((int4*)pk)[0];
        dst[1] = ((int4*)pk)[1];
    } else if (bid < 3840) {
        int idx = bid - 3072;                    // 0..767
        int n0 = (idx % 48) * 64;
        int k0 = (idx / 48) * 64;
        int tx = tid & 63, tg = tid >> 6;
#pragma unroll
        for (int i = 0; i < 16; ++i) {
            int r = tg + i * 4;
            tsm[r][tx] = __float2bfloat16(W[(size_t)(k0 + r) * 3072 + n0 + tx]);
        }
        __syncthreads();
#pragma unroll
        for (int i = 0; i < 16; ++i) {
            int r = tg + i * 4;
            Wt[(size_t)(n0 + r) * 1024 + k0 + tx] = tsm[tx][r];
        }
    } else {
        int idx = (bid - 3840) * 256 + tid;      // 0..65535
        int n  = idx & (NN - 1);
        int bh = idx >> 11;
        int h  = bh & (HH - 1);
        int b  = bh >> 4;
        float acc = 0.f;
#pragma unroll
        for (int c = 0; c < 3; ++c)
            acc += coords[(size_t)(b * NN + n) * 3 + c] * relw[h * 3 + c];
        cpn[idx] = __float2bfloat16(-LOG2E * acc);
    }
}

// ---------------------------------------------------------------------------
// qkv GEMM (R7 version): 128x128 tile, BK=32, single-buffered, glds w=16,
// swizzle c^=((row>>1)&3), XCD m-grouped block swizzle. V written DIRECTLY
// TRANSPOSED (bh,d,n); q pre-scaled by SCALE_Q.
// ---------------------------------------------------------------------------
__global__ __launch_bounds__(256) void qkv_gemm(const bf16* __restrict__ X,
                                                const bf16* __restrict__ W,
                                                const float* __restrict__ bq,
                                                bf16* __restrict__ qo,
                                                bf16* __restrict__ ko,
                                                bf16* __restrict__ vt) {
    __shared__ __align__(16) bf16 As[128 * 32];
    __shared__ __align__(16) bf16 Bs[128 * 32];
    const int tid  = threadIdx.x;
    const int gid  = blockIdx.x + blockIdx.y * 24;   // 0..767
    const int xcd  = gid & 7;                        // HW round-robin XCD
    const int idx  = gid >> 3;                       // 0..95 within XCD
    const int n0   = (idx >> 2) * 128;               // n-block 0..23 (m-fastest order)
    const int m0   = (xcd * 4 + (idx & 3)) * 128;    // 4 contiguous m-panels per XCD
    const int wave = tid >> 6, lane = tid & 63, l15 = lane & 15, quad = lane >> 4;
    const int wm   = wave >> 1, wn = wave & 1;

    f32x4 acc[4][4];
    const f32x4 z4 = {0.f, 0.f, 0.f, 0.f};
#pragma unroll
    for (int i = 0; i < 4; ++i)
#pragma unroll
        for (int j = 0; j < 4; ++j) acc[i][j] = z4;

    for (int kt = 0; kt < 1024; kt += 32) {
        __syncthreads();
#pragma unroll
        for (int j = 0; j < 2; ++j) {
            int s   = (wave * 2 + j) * 64 + lane;       // 0..511
            int row = s >> 2;                           // 0..127
            int c   = (s & 3) ^ ((row >> 1) & 3);       // swizzled col-block
            glds16(X + (size_t)(m0 + row) * 1024 + kt + c * 8, As + (wave * 2 + j) * 512);
            glds16(W + (size_t)(n0 + row) * 1024 + kt + c * 8, Bs + (wave * 2 + j) * 512);
        }
        __syncthreads();

        bf16x8 a[4], b[4];
#pragma unroll
        for (int mt = 0; mt < 4; ++mt) {
            int ra = wm * 64 + mt * 16 + l15;
            a[mt] = *(const bf16x8*)&As[ra * 32 + ((quad ^ ((ra >> 1) & 3)) * 8)];
        }
#pragma unroll
        for (int nt = 0; nt < 4; ++nt) {
            int rb = wn * 64 + nt * 16 + l15;
            b[nt] = *(const bf16x8*)&Bs[rb * 32 + ((quad ^ ((rb >> 1) & 3)) * 8)];
        }
#pragma unroll
        for (int mt = 0; mt < 4; ++mt)
#pragma unroll
            for (int nt = 0; nt < 4; ++nt)
                acc[mt][nt] = __builtin_amdgcn_mfma_f32_16x16x32_bf16(a[mt], b[nt], acc[mt][nt], 0, 0, 0);
    }

#pragma unroll
    for (int nt = 0; nt < 4; ++nt) {
        int c    = n0 + wn * 64 + nt * 16 + l15;   // 0..3071, tsel uniform per nt
        int tsel = c >> 10;
        int rem  = c & 1023;
        int h    = rem >> 6, d = rem & 63;
        float bias = bq[c];
        float qs   = (tsel == 0) ? SCALE_Q : 1.0f;
#pragma unroll
        for (int mt = 0; mt < 4; ++mt)
#pragma unroll
            for (int r = 0; r < 4; ++r) {
                int m = m0 + wm * 64 + mt * 16 + quad * 4 + r;   // 0..4095
                int b = m >> 11, n = m & (NN - 1);
                bf16 val = __float2bfloat16((acc[mt][nt][r] + bias) * qs);
                if (tsel == 2)
                    vt[((size_t)(b * HH + h) * HD + d) * NN + n] = val;
                else
                    ((tsel == 1) ? ko : qo)[((size_t)(b * HH + h) * NN + n) * HD + d] = val;
            }
    }
}

// ---------------------------------------------------------------------------
// flash attention v9: v8 + CROSS-TILE PV PIPELINE. PV(T) is deferred into
// tile T+1 and its 8 MFMAs are interleaved with QK(T+1)'s 8 MFMAs — two
// independent chains fill each other's latency (v8 exposed ~16cy/MFMA
// dependent-chain latency). V(T) fragments are captured into registers
// before the tile barrier (race-free: stage(T+2) overwrites Vs[cur] only
// after T+1's barrier); P(T) packed words persist across the barrier.
// Epilogue runs PV(31). LDS 36 KB, bank-conflict-free swizzles (R11).
// ---------------------------------------------------------------------------
__global__ __launch_bounds__(512, 4) void attn(const bf16* __restrict__ Q,
                                               const bf16* __restrict__ K,
                                               const bf16* __restrict__ Vt_g,
                                               const bf16* __restrict__ cpn_g,
                                               const unsigned* __restrict__ pbh,
                                               float* __restrict__ out) {
    __shared__ __align__(16) bf16 Ks[2][64 * 64];
    __shared__ __align__(16) bf16 Vs[2][64 * 64];      // [d][key]
    __shared__ __align__(16) bf16 cpl[NN];             // -log2e * cp[bh][*]
    const int tid  = threadIdx.x;
    const int Qb   = blockIdx.x;           // 0..15
    const int bh   = blockIdx.y;           // 0..31
    const int b    = bh >> 4, h = bh & 15;
    const int q0   = Qb * 128;
    const int wave = tid >> 6, lane = tid & 63, l15 = lane & 15, quad = lane >> 4;
    const size_t base = (size_t)bh * NN * HD;

    // stage cp row (4 KB) with waves 0..3 (wave-uniform branch)
    if (wave < 4)
        glds16(cpn_g + bh * NN + (wave * 64 + lane) * 8, cpl + wave * 512);

    // Q fragments: 16 q-rows per wave, in registers for the whole kernel
    const int qrow = q0 + wave * 16 + l15;
    bf16x8 qf0 = *(const bf16x8*)&Q[base + (size_t)qrow * HD + quad * 8];
    bf16x8 qf1 = *(const bf16x8*)&Q[base + (size_t)qrow * HD + 32 + quad * 8];

    // staging geometry (one glds per buffer per wave); K and V use
    // DIFFERENT swizzles (K: fstage, V: row&7)
    const int ps    = wave * 64 + lane;     // 0..511
    const int prow  = ps >> 3;              // 0..63
    const int pcolV = (ps & 7) ^ (prow & 7);
    const int pcolK = (ps & 7) ^ ((prow & 3) | (((prow >> 3) & 1) << 2));

    // prologue: stage tile 0 into buffer 0
    glds16(K    + base + (size_t)prow * HD + pcolK * 8, Ks[0] + wave * 512);
    glds16(Vt_g + base + (size_t)prow * NN + pcolV * 8, Vs[0] + wave * 512);

    // bias: permuted packed bf16 (permuted-key layout), register dbuf.
    const unsigned* bptr = pbh + ((((size_t)Qb * 32) * 8 + wave) * 64 + lane) * 8;
    unsigned bvA[8], bvB[8];
    *(int4*)&bvA[0] = ((const int4*)bptr)[0];
    *(int4*)&bvA[4] = ((const int4*)bptr)[1];

    // loop-invariant K-read geometry
    const int lrow = ((l15 >> 2) << 3) + (l15 & 3);          // row offset per g
    const int fK   = (l15 & 3) | (((l15 >> 2) & 1) << 2);    // read swizzle (conflict-free)
    const int ck0  = (quad ^ fK) * 8;                        // chunk 0..3
    const int ck1  = ((4 + quad) ^ fK) * 8;                  // chunk 4..7

    const f32x4 z4 = {0.f, 0.f, 0.f, 0.f};
    float l_acc = 0.f;
    f32x4 o[4];
#pragma unroll
    for (int t = 0; t < 4; ++t) o[t] = z4;

    // cross-tile pipeline state: P(T) packed words + V(T) fragments
    union { unsigned u[4]; bf16x8 v; } pB0, pB1;
    bf16x8 pvf0[4], pvf1[4];

#define ATTN_TILE(T, CUR, BVC, BVN, FIRST)                                        \
    {                                                                             \
        __syncthreads();   /* buf[CUR] ready (vmcnt drained); buf[CUR^1] free */  \
        if ((T) < 31) {    /* prefetch K/V tile T+1 and bias T+1 */               \
            int kk1 = ((T) + 1) * 64;                                             \
            glds16(K    + base + (size_t)(kk1 + prow) * HD + pcolK * 8,           \
                   Ks[(CUR) ^ 1] + wave * 512);                                   \
            glds16(Vt_g + base + (size_t)prow * NN + kk1 + pcolV * 8,             \
                   Vs[(CUR) ^ 1] + wave * 512);                                   \
            const unsigned* bp = bptr + (size_t)((T) + 1) * 4096;                 \
            *(int4*)&BVN[0] = ((const int4*)bp)[0];                               \
            *(int4*)&BVN[4] = ((const int4*)bp)[1];                               \
        }                                                                         \
        /* --- QK(T) interleaved with PV(T-1): independent MFMA chains */         \
        f32x4 s4v[4];                                                             \
        __builtin_amdgcn_s_setprio(1);                                            \
        _Pragma("unroll")                                                         \
        for (int g = 0; g < 4; ++g) {                                             \
            const int kb = (g >> 1) * 32 + (g & 1) * 4;                           \
            ushort4 mgu = *(const ushort4*)&cpl[(T) * 64 + kb + quad * 8];        \
            unsigned ba = BVC[g * 2], bb2 = BVC[g * 2 + 1];                       \
            f32x4 c0;                                                             \
            c0[0] = __builtin_bit_cast(float, ba << 16)                           \
                  + __builtin_bit_cast(float, (unsigned)mgu.x << 16);             \
            c0[1] = __builtin_bit_cast(float, ba & 0xffff0000u)                   \
                  + __builtin_bit_cast(float, (unsigned)mgu.y << 16);             \
            c0[2] = __builtin_bit_cast(float, bb2 << 16)                          \
                  + __builtin_bit_cast(float, (unsigned)mgu.z << 16);             \
            c0[3] = __builtin_bit_cast(float, bb2 & 0xffff0000u)                  \
                  + __builtin_bit_cast(float, (unsigned)mgu.w << 16);             \
            int krow = kb + lrow;                                                 \
            bf16x8 k0 = *(const bf16x8*)&Ks[(CUR)][krow * 64 + ck0];              \
            bf16x8 k1 = *(const bf16x8*)&Ks[(CUR)][krow * 64 + ck1];              \
            s4v[g] = __builtin_amdgcn_mfma_f32_16x16x32_bf16(k0, qf0, c0, 0, 0, 0);        \
            s4v[g] = __builtin_amdgcn_mfma_f32_16x16x32_bf16(k1, qf1, s4v[g], 0, 0, 0);    \
            if (!(FIRST)) {                                                       \
                o[g] = __builtin_amdgcn_mfma_f32_16x16x32_bf16(pvf0[g], pB0.v, o[g], 0, 0, 0); \
                o[g] = __builtin_amdgcn_mfma_f32_16x16x32_bf16(pvf1[g], pB1.v, o[g], 0, 0, 0); \
            }                                                                     \
        }                                                                         \
        __builtin_amdgcn_s_setprio(0);                                            \
        /* --- softmax(T): exp2 + pack into persistent P words */                 \
        _Pragma("unroll")                                                         \
        for (int g = 0; g < 4; ++g) {                                             \
            f32x4 e;                                                              \
            e[0] = __builtin_amdgcn_exp2f(s4v[g][0]);                             \
            e[1] = __builtin_amdgcn_exp2f(s4v[g][1]);                             \
            e[2] = __builtin_amdgcn_exp2f(s4v[g][2]);                             \
            e[3] = __builtin_amdgcn_exp2f(s4v[g][3]);                             \
            l_acc += (e[0] + e[1]) + (e[2] + e[3]);                               \
            unsigned w0 = (unsigned)bfu(e[0]) | ((unsigned)bfu(e[1]) << 16);      \
            unsigned w1 = (unsigned)bfu(e[2]) | ((unsigned)bfu(e[3]) << 16);      \
            if (g < 2) { pB0.u[g * 2] = w0; pB0.u[g * 2 + 1] = w1; }              \
            else       { pB1.u[(g - 2) * 2] = w0; pB1.u[(g - 2) * 2 + 1] = w1; }  \
        }                                                                         \
        /* --- capture V(T) fragments for PV in tile T+1 (race-free) */           \
        _Pragma("unroll")                                                         \
        for (int tt = 0; tt < 4; ++tt) {                                          \
            int drow = tt * 16 + l15, sw2 = drow & 7;                             \
            pvf0[tt] = *(const bf16x8*)&Vs[(CUR)][drow * 64 + ((quad ^ sw2) * 8)];         \
            pvf1[tt] = *(const bf16x8*)&Vs[(CUR)][drow * 64 + (((4 + quad) ^ sw2) * 8)];   \
        }                                                                         \
    }

    ATTN_TILE(0, 0, bvA, bvB, 1)
    ATTN_TILE(1, 1, bvB, bvA, 0)
    for (int t = 2; t < 32; t += 2) {
        ATTN_TILE(t,     0, bvA, bvB, 0)
        ATTN_TILE(t + 1, 1, bvB, bvA, 0)
    }
#undef ATTN_TILE

    // epilogue: PV(31) from persisted P words + V fragments
#pragma unroll
    for (int tt = 0; tt < 4; ++tt) {
        o[tt] = __builtin_amdgcn_mfma_f32_16x16x32_bf16(pvf0[tt], pB0.v, o[tt], 0, 0, 0);
        o[tt] = __builtin_amdgcn_mfma_f32_16x16x32_bf16(pvf1[tt], pB1.v, o[tt], 0, 0, 0);
    }

    // l: reduce across the 4 quads holding the same q (=l15)
    l_acc += __shfl_xor(l_acc, 16, 64);
    l_acc += __shfl_xor(l_acc, 32, 64);
    const float inv = 1.0f / l_acc;

    // stores: o[tt][r] = O[d=tt*16+quad*4+r][q=l15] -> dwordx4 per tt
    const int qq = q0 + wave * 16 + l15;
#pragma unroll
    for (int tt = 0; tt < 4; ++tt) {
        f32x4 ov;
        ov[0] = o[tt][0] * inv; ov[1] = o[tt][1] * inv;
        ov[2] = o[tt][2] * inv; ov[3] = o[tt][3] * inv;
        *(f32x4*)&out[((size_t)(b * NN + qq)) * DD + h * HD + tt * 16 + quad * 4] = ov;
    }
}

// ---------------------------------------------------------------------------
extern "C" void kernel_launch(void* const* d_in, const int* in_sizes, int n_in,
                              void* d_out, int out_size, void* d_ws, size_t ws_size,
                              hipStream_t stream) {
    const float* x      = (const float*)d_in[0];
    const float* coords = (const float*)d_in[1];
    const float* abias  = (const float*)d_in[2];
    const float* Wqkv   = (const float*)d_in[3];
    const float* bqkv   = (const float*)d_in[4];
    const float* relw   = (const float*)d_in[5];
    float* out = (float*)d_out;

    char* ws = (char*)d_ws;
    bf16*     xb  = (bf16*)(ws);                      // 8 MB
    bf16*     qw  = (bf16*)(ws + 8388608);            // 8 MB
    bf16*     kw  = (bf16*)(ws + 16777216);           // 8 MB
    bf16*     vt  = (bf16*)(ws + 25165824);           // 8 MB (bh,d,n) via gemm epilogue
    bf16*     Wt  = (bf16*)(ws + 33554432);           // 6 MB
    unsigned* pbh = (unsigned*)(ws + 39845888);       // 8.4 MB permuted bias packed bf16
    bf16*     cpb = (bf16*)(ws + 56623104);           // 128 KB

    prep    <<<dim3(4096),   256, 0, stream>>>(x, abias, Wqkv, coords, relw,
                                               xb, pbh, Wt, cpb);
    qkv_gemm<<<dim3(24, 32), 256, 0, stream>>>(xb, Wt, bqkv, qw, kw, vt);
    attn    <<<dim3(16, 32), 512, 0, stream>>>(qw, kw, vt, cpb, pbh, out);
}